// Round 11
// baseline (670.826 us; speedup 1.0000x reference)
//
#include <hip/hip_runtime.h>
#include <string.h>

// Quantum classifier fwd: 14 qubits, batch 4096, 6 StronglyEntanglingLayers.
// Round 11 = R8's PROVEN conflict-free GF(2) tables/addressing (2.1e6 conflicts)
//          + R10's register discipline (pack C->u32 pre-barrier: no spills).
// MFMA formulation: pass = 16x16 complex unitary on 1024 cols; per 16-col tile
// two v_mfma_f32_16x16x32_f16 (re/im A-planes); B-frag = packed {re,im} f16
// amps from LDS (16 b32 reads/tile-group, 2-way bank = free); role swaps via
// popc (VALU has headroom); writes shaped by R8's A5 rank criterion.

#define NQ     14
#define NL     6
#define NSTATE 16384
#define BLOCK  1024
#define NPASS  24

typedef unsigned u32;
typedef _Float16 h8  __attribute__((ext_vector_type(8)));
typedef _Float16 h2v __attribute__((ext_vector_type(2)));
typedef __fp16   p2v __attribute__((ext_vector_type(2)));
typedef float    f4  __attribute__((ext_vector_type(4)));

struct AllTables {
  u32 rhoc[NPASS][4];   // pass roles compressed to col-index space (10-bit)
  u32 wCol[NPASS-1][10];// write map: images of col-index bits (14-bit addrs)
  u32 wGam[NPASS-1][4]; // write map: images of gamma bits
  u32 a0[10], b0[16];   // init scatter (= W_0 over original basis)
  u32 erlo[2], erhi[2]; // expectation sign rows (col-index / gamma spaces)
  int check;
};

// gamma bit i lives at address bit GB[i]; col-index bit j at CB[j]
static const int GBh[4]  = {12,13,4,5};
static const int CBh[10] = {0,1,2,3,6,7,8,9,10,11};

// ---------------- host-side GF(2) machinery (R8, verified) ----------------
namespace qct {

struct GF2 { unsigned short r[NQ]; };
static GF2 gf2_id(){ GF2 m{}; for(int i=0;i<NQ;++i) m.r[i]=(unsigned short)(1u<<i); return m; }
static GF2 gf2_mul(const GF2& A, const GF2& B){
  GF2 C{};
  for(int i=0;i<NQ;++i){ u32 v=0; for(int k=0;k<NQ;++k) if((A.r[i]>>k)&1) v^=B.r[k]; C.r[i]=(unsigned short)v; }
  return C;
}
static GF2 cnotF(int c, int t){
  GF2 F=gf2_id();
  F.r[13-t]=(unsigned short)((1u<<(13-t))|(1u<<(13-c)));
  return F;
}

struct Lin { u32 c[14]; };
static u32 lapply(const Lin& L, u32 x){ u32 r=0; for(int j=0;j<14;++j) if((x>>j)&1u) r^=L.c[j]; return r; }
static Lin lcompose(const Lin& A, const Lin& B){ Lin R{}; for(int j=0;j<14;++j) R.c[j]=lapply(A,B.c[j]); return R; }
static Lin lident(){ Lin L{}; for(int j=0;j<14;++j) L.c[j]=1u<<j; return L; }
static Lin linverse(const Lin& L){
  u32 rows[14]={0}, inv[14]={0};
  for(int i=0;i<14;++i){ u32 r=0; for(int j=0;j<14;++j) r|=((L.c[j]>>i)&1u)<<j; rows[i]=r; inv[i]=1u<<i; }
  for(int col=0; col<14; ++col){
    int piv=-1;
    for(int i=col;i<14;++i) if((rows[i]>>col)&1u){piv=i;break;}
    if(piv<0) continue;
    u32 tr=rows[col]; rows[col]=rows[piv]; rows[piv]=tr;
    tr=inv[col]; inv[col]=inv[piv]; inv[piv]=tr;
    for(int i=0;i<14;++i) if(i!=col && ((rows[i]>>col)&1u)){ rows[i]^=rows[col]; inv[i]^=inv[col]; }
  }
  Lin R{};
  for(int j=0;j<14;++j){ u32 cc=0; for(int i=0;i<14;++i) cc|=((inv[i]>>j)&1u)<<i; R.c[j]=cc; }
  return R;
}
static u32 roletrans(const Lin& invS, u32 rho){
  u32 r=0;
  for(int j=0;j<14;++j) r |= (u32)(__builtin_popcount(invS.c[j]&rho)&1) << j;
  return r;
}

struct Span14 { u32 E[14]; u32 EI[14]; };
static void span_init(Span14& S){ for(int i=0;i<14;++i){S.E[i]=0;S.EI[i]=0;} }
static int top14(u32 v){ for(int i=13;i>=0;--i) if((v>>i)&1u) return i; return -1; }
struct Red { u32 v; u32 img; };
static Red span_reduce(const Span14& S, u32 v){
  u32 img=0;
  while(v){
    int b=top14(v);
    if(!S.E[b]) break;
    v^=S.E[b]; img^=S.EI[b];
  }
  Red r; r.v=v; r.img=img; return r;
}
static bool span_add(Span14& S, u32 v, u32 img){
  Red r=span_reduce(S,v);
  if(!r.v) return false;
  int b=top14(r.v);
  S.E[b]=r.v; S.EI[b]=img^r.img;
  return true;
}
static bool span_has(const Span14& S, u32 v){ Red r=span_reduce(S,v); return r.v==0; }

static u32 cmprs_col(u32 v){ u32 r=0; for(int j=0;j<10;++j) r |= ((v>>CBh[j])&1u)<<j; return r; }
static u32 cmprs_gam(u32 v){ u32 r=0; for(int i=0;i<4;++i)  r |= ((v>>GBh[i])&1u)<<i; return r; }

static AllTables make_all(){
  AllTables T; memset(&T,0,sizeof(T)); T.check=1;
  u32 MU[84]={0}, RHO[84]={0}; u32 er0=0, er1=0;
  {
    GF2 G=gf2_id(), H=gf2_id();
    for(int l=0;l<NL;++l){
      for(int q=0;q<NQ;++q){
        int idx=l*NQ+q, bit=13-q;
        u32 m=0;
        for(int r=0;r<NQ;++r) m |= ((u32)((H.r[r]>>bit)&1u))<<r;
        MU[idx]=m; RHO[idx]=G.r[bit];
        if(!(__builtin_popcount(m & (u32)G.r[bit])&1)) T.check=0;
      }
      int rr=(l%(NQ-1))+1;
      GF2 C=gf2_id(), Ci=gf2_id();
      for(int q=0;q<NQ;++q){
        GF2 F=cnotF(q,(q+rr)%NQ);
        C=gf2_mul(C,F); Ci=gf2_mul(F,Ci);
      }
      G=gf2_mul(Ci,G); H=gf2_mul(H,C);
    }
    er0=G.r[13]; er1=G.r[12];
  }
  Lin S=lident();
  u32 lo_prev[4]={0,0,0,0};
  for(int b=0;b<NPASS;++b){
    const int layer=b>>2, g=b&3;
    const int ng=(g<3)?4:2, q0=(g<3)?4*g:12;
    u32 cin[4]={0,0,0,0};
    for(int i=0;i<ng;++i) cin[i]=lapply(S,MU[layer*NQ+q0+i]);
    if(ng==2){
      // free directions (slots 2,3): orthogonal to both real roles, independent
      Lin invS=linverse(S);
      u32 rp0=roletrans(invS,RHO[layer*NQ+12]);
      u32 rp1=roletrans(invS,RHO[layer*NQ+13]);
      int got=0;
      for(u32 cs=1; cs<16384u && got<2; ++cs){
        u32 v=(cs*2654435761u)&16383u;
        if(!v) continue;
        if(__builtin_popcount(v&rp0)&1) continue;
        if(__builtin_popcount(v&rp1)&1) continue;
        Span14 tmp; span_init(tmp); bool ind=true;
        for(int i=0;i<2+got;++i) if(!span_add(tmp,cin[i],0)) ind=false;
        if(ind){ cin[2+got]=v; ++got; }
      }
      if(got<2) T.check=0;
    }
    // ---- deterministic W build (R8) ----
    Span14 SI; span_init(SI);
    Span14 IM; span_init(IM);
    bool ok=true;
    for(int i=0;i<4;++i){
      if(!span_add(SI,cin[i],1u<<GBh[i])) ok=false;
      if(!span_add(IM,1u<<GBh[i],0))      ok=false;
    }
    u32 wg[4]={0,0,0,0};
    for(int i=0;i<4 && ok;++i){            // define W on gamma domain bits
      u32 d=1u<<GBh[i];
      Red rr=span_reduce(SI,d);
      if(rr.v==0){ wg[i]=rr.img; continue; }
      u32 img=0; bool f=false;
      for(u32 fm=0; fm<16384u && !f; ++fm){ u32 cand=d^fm; if(cand && !span_has(IM,cand)){img=cand;f=true;} }
      if(!f){ok=false;break;}
      span_add(SI,d,img); span_add(IM,img,0); wg[i]=img;
    }
    u32 X[4]={0,0,0,0};
    for(int j=0;j<4;++j){ u32 xx=0; for(int i=0;i<4;++i) if((lo_prev[i]>>j)&1u) xx^=wg[i]; X[j]=xx; }
    for(int j=0;j<4 && ok;++j){            // n-bits: shape write banks
      u32 d=1u<<CBh[j];
      if(span_has(SI,d)) continue;
      u32 pref=((1u<<j)^X[j])&16383u;
      u32 img=0; bool f=false;
      for(u32 fm=0; fm<512u && !f; ++fm){ u32 cand=(pref^(fm<<5))&16383u; if(cand && !span_has(IM,cand)){img=cand;f=true;} }
      for(u32 fm=0; fm<16384u && !f; ++fm){ u32 cand=(pref^fm)&16383u; if(cand && !span_has(IM,cand)){img=cand;f=true;} }
      if(!f){ok=false;break;}
      span_add(SI,d,img); span_add(IM,img,0);
    }
    for(int j=4;j<10 && ok;++j){           // completion on remaining col bits
      u32 d=1u<<CBh[j];
      if(span_has(SI,d)) continue;
      u32 img=0; bool f=false;
      for(u32 fm=0; fm<16384u && !f; ++fm){ u32 cand=d^fm; if(cand && !span_has(IM,cand)){img=cand;f=true;} }
      if(!f){ok=false;break;}
      span_add(SI,d,img); span_add(IM,img,0);
    }
    Lin W=lident();
    if(ok){
      for(int jb=0;jb<14;++jb){
        Red rr=span_reduce(SI,1u<<jb);
        if(rr.v){ok=false;break;}
        W.c[jb]=rr.img;
      }
    }
    if(!ok) T.check=0;
    if(b==0){
      for(int j=0;j<10;++j) T.a0[j]=W.c[j];
      for(int gm=0;gm<16;++gm){ u32 xx=0; for(int i=0;i<4;++i) if((gm>>i)&1) xx^=W.c[10+i]; T.b0[gm]=xx; }
    } else {
      for(int j=0;j<10;++j) T.wCol[b-1][j]=W.c[CBh[j]];
      for(int i=0;i<4;++i)  T.wGam[b-1][i]=W.c[GBh[i]];
    }
    S=lcompose(W,S);
    Lin invS2=linverse(S);
    for(int i=0;i<4;++i) T.rhoc[b][i]=0;
    for(int i=0;i<ng;++i){
      u32 rp=roletrans(invS2,RHO[layer*NQ+q0+i]);
      for(int ii=0;ii<4;++ii){
        u32 bit=(rp>>GBh[ii])&1u;
        if(bit != (u32)((ii==i)?1:0)) T.check=0;            // canonical role
      }
      if(lapply(S,MU[layer*NQ+q0+i]) != (1u<<GBh[i])) T.check=0; // canonical mask
      T.rhoc[b][i]=cmprs_col(rp);
    }
    for(int i=0;i<4;++i) lo_prev[i]=T.rhoc[b][i];
  }
  Lin invF=linverse(S);
  u32 e0=roletrans(invF,er0), e1=roletrans(invF,er1);
  T.erlo[0]=cmprs_col(e0); T.erhi[0]=cmprs_gam(e0);
  T.erlo[1]=cmprs_col(e1); T.erhi[1]=cmprs_gam(e1);
  return T;
}

} // namespace qct

// ---------------- device code ----------------

// pre-kernel: per-lane MFMA A-fragments (identical to R8 — verified).
__global__ void gate_kernel(const float* __restrict__ wgt, u32* __restrict__ gA){
  __shared__ float us[84][8];
  const int t = threadIdx.x;
  if (t < 84) {
    const float phi=wgt[3*t+0], th=wgt[3*t+1], om=wgt[3*t+2];
    const float ct=cosf(0.5f*th), stt=sinf(0.5f*th);
    const float aa=0.5f*(phi+om), bb=0.5f*(phi-om);
    const float ca=cosf(aa), sa=sinf(aa);
    const float cb=cosf(bb), sb=sinf(bb);
    us[t][0]= ca*ct;  us[t][1]=-sa*ct;
    us[t][2]=-cb*stt; us[t][3]=-sb*stt;
    us[t][4]= cb*stt; us[t][5]=-sb*stt;
    us[t][6]= ca*ct;  us[t][7]= sa*ct;
  }
  __syncthreads();
  for (int task = t; task < NPASS*64; task += (int)blockDim.x) {
    const int p = task >> 6, l = task & 63;
    const int m = l & 15, gb = ((l>>4)&3)*4;
    const int layer = p>>2, g = p&3;
    const int ng = (g<3)?4:2, q0 = (g<3)?4*g:12;
    u32 rre[4], rim[4];
    for (int r = 0; r < 4; ++r) {
      const int gam = gb + r;
      float ure=1.f, uim=0.f; bool zero=false;
      for (int sl = 0; sl < 4; ++sl) {
        const int mb=(m>>sl)&1, cbit=(gam>>sl)&1;
        float fre, fim;
        if (sl < ng) {
          const float* u = us[layer*NQ + q0 + sl];
          fre = u[(mb*2+cbit)*2]; fim = u[(mb*2+cbit)*2+1];
        } else {
          if (mb != cbit) zero = true;
          fre = 1.f; fim = 0.f;
        }
        const float nre = ure*fre - uim*fim;
        const float nim = ure*fim + uim*fre;
        ure = nre; uim = nim;
      }
      if (zero) { ure = 0.f; uim = 0.f; }
      h2v a; a.x=(_Float16)ure;  a.y=(_Float16)(-uim);
      h2v bq; bq.x=(_Float16)uim; bq.y=(_Float16)ure;
      __builtin_memcpy(&rre[r], &a, 4);
      __builtin_memcpy(&rim[r], &bq, 4);
    }
    u32* o0 = gA + ((size_t)(p*2+0)*64 + l)*4;
    u32* o1 = gA + ((size_t)(p*2+1)*64 + l)*4;
    o0[0]=rre[0]; o0[1]=rre[1]; o0[2]=rre[2]; o0[3]=rre[3];
    o1[0]=rim[0]; o1[1]=rim[1]; o1[2]=rim[2]; o1[3]=rim[3];
  }
}

extern "C" __global__ void __launch_bounds__(BLOCK, 8)
qc_kernel(const float* __restrict__ x, const uint4* __restrict__ gA,
          float* __restrict__ out, const AllTables T){
  extern __shared__ u32 lds[];                // 16384 u32 = 64 KiB (state)
  const u32 t = threadIdx.x;
  const u32 s = blockIdx.x;
  const u32 l = t & 63u, w = t >> 6;
  const u32 q = (l >> 4) & 3u, n = l & 15u;

  // --- encoding angles (LDS scratch overlaps state; barrier-ordered) ---
  float* encf = reinterpret_cast<float*>(lds);
  if (t < NQ) {
    const float h = x[s*NQ + t] * 1.57079632679489662f;
    encf[2*t]   = cosf(h);
    encf[2*t+1] = sinf(h);
  }
  __syncthreads();

  // --- init: product state scattered through W_0 ---
  {
    float pr = 1.0f;
    #pragma unroll
    for (int b = 0; b < 10; ++b) pr *= encf[2*(13-b) + ((t>>b)&1u)];
    float e[8];
    #pragma unroll
    for (int j = 0; j < 8; ++j) e[j] = encf[j];
    __syncthreads();
    u32 a0f = 0;
    #pragma unroll
    for (int j = 0; j < 10; ++j) a0f ^= (0u-((t>>j)&1u)) & T.a0[j];
    #pragma unroll
    for (int i = 0; i < 16; ++i) {
      float vv = pr;
      #pragma unroll
      for (int bq = 0; bq < 4; ++bq) vv *= e[2*(3-bq) + ((i>>bq)&1)];
      h2v hv; hv.x = (_Float16)vv; hv.y = (_Float16)0.0f;
      u32 av; __builtin_memcpy(&av, &hv, 4);
      lds[a0f ^ T.b0[i]] = av;
    }
  }
  __syncthreads();

  const f4 z = {0.f, 0.f, 0.f, 0.f};

  // --- passes 0..22: read (R8 pattern) + MFMA + pack pre-barrier + scatter ---
  #pragma unroll 1
  for (int k = 0; k < NPASS-1; ++k) {
    const uint4 ar4 = gA[(size_t)(k*2+0)*64 + l];
    const uint4 ai4 = gA[(size_t)(k*2+1)*64 + l];
    h8 aRe, aIm;
    __builtin_memcpy(&aRe, &ar4, 16);
    __builtin_memcpy(&aIm, &ai4, 16);
    const u32 r0 = T.rhoc[k][0], r1 = T.rhoc[k][1];
    const u32 r2 = T.rhoc[k][2], r3 = T.rhoc[k][3];

    u32 swt[4];
    u32 po[4][4];
    #pragma unroll
    for (int jt = 0; jt < 4; ++jt) {
      const u32 ci = (w<<6) | ((u32)jt<<4) | n;               // col index
      const u32 sw = (u32)(__popc(ci&r0)&1) | ((u32)(__popc(ci&r1)&1)<<1)
                   | ((u32)(__popc(ci&r2)&1)<<2) | ((u32)(__popc(ci&r3)&1)<<3);
      swt[jt] = sw;
      const u32 gx  = (q<<2) ^ sw;
      const u32 gsw = ((gx&3u)<<12) | ((gx&12u)<<2);          // gamma scatter
      const u32 cp  = n | ((((w<<2)|(u32)jt))<<6);            // col scatter
      const u32 base = cp ^ gsw;
      uint4 bv;
      bv.x = lds[base];
      bv.y = lds[base ^ (1u<<12)];
      bv.z = lds[base ^ (2u<<12)];
      bv.w = lds[base ^ (3u<<12)];
      h8 bf; __builtin_memcpy(&bf, &bv, 16);
      f4 rf1 = __builtin_amdgcn_mfma_f32_16x16x32_f16(aRe, bf, z, 0, 0, 0);
      f4 rf2 = __builtin_amdgcn_mfma_f32_16x16x32_f16(aIm, bf, z, 0, 0, 0);
      #pragma unroll
      for (int rr = 0; rr < 4; ++rr) {
        p2v hv = __builtin_amdgcn_cvt_pkrtz(rf1[rr], rf2[rr]);
        __builtin_memcpy(&po[jt][rr], &hv, 4);
      }
    }

    __syncthreads();   // all reads done before any scatter lands

    u32 nf = 0;
    #pragma unroll
    for (int j = 0; j < 4; ++j) nf ^= (0u-((n>>j)&1u)) & T.wCol[k][j];
    u32 wf = 0;
    #pragma unroll
    for (int j = 0; j < 4; ++j) wf ^= (0u-((w>>j)&1u)) & T.wCol[k][6+j];
    const u32 wgq = ((q&1u)?T.wGam[k][2]:0u) ^ ((q&2u)?T.wGam[k][3]:0u);
    const u32 baseW = nf ^ wf ^ wgq;
    #pragma unroll
    for (int jt = 0; jt < 4; ++jt) {
      const u32 sw = swt[jt];
      const u32 swf = ((sw&1u)?T.wGam[k][0]:0u) ^ ((sw&2u)?T.wGam[k][1]:0u)
                    ^ ((sw&4u)?T.wGam[k][2]:0u) ^ ((sw&8u)?T.wGam[k][3]:0u);
      const u32 tf = ((jt&1)?T.wCol[k][4]:0u) ^ ((jt&2)?T.wCol[k][5]:0u);
      const u32 ab = baseW ^ swf ^ tf;
      const u32 g1 = T.wGam[k][0], g2 = T.wGam[k][1];
      lds[ab]         = po[jt][0];
      lds[ab^g1]      = po[jt][1];
      lds[ab^g2]      = po[jt][2];
      lds[ab^g1^g2]   = po[jt][3];
    }
    __syncthreads();  // scatter complete before next pass reads
  }

  // --- pass 23 (2-gate) fused with expectation, no store ---
  float z0 = 0.f, z1 = 0.f;
  {
    const int k = NPASS-1;
    const uint4 ar4 = gA[(size_t)(k*2+0)*64 + l];
    const uint4 ai4 = gA[(size_t)(k*2+1)*64 + l];
    h8 aRe, aIm;
    __builtin_memcpy(&aRe, &ar4, 16);
    __builtin_memcpy(&aIm, &ai4, 16);
    const u32 r0 = T.rhoc[k][0], r1 = T.rhoc[k][1];
    const u32 r2 = T.rhoc[k][2], r3 = T.rhoc[k][3];
    const u32 gq0 = (u32)(__popc((q<<2) & T.erhi[0]) & 1);
    const u32 gq1 = (u32)(__popc((q<<2) & T.erhi[1]) & 1);
    #pragma unroll
    for (int jt = 0; jt < 4; ++jt) {
      const u32 ci = (w<<6) | ((u32)jt<<4) | n;
      const u32 sw = (u32)(__popc(ci&r0)&1) | ((u32)(__popc(ci&r1)&1)<<1)
                   | ((u32)(__popc(ci&r2)&1)<<2) | ((u32)(__popc(ci&r3)&1)<<3);
      const u32 gx  = (q<<2) ^ sw;
      const u32 gsw = ((gx&3u)<<12) | ((gx&12u)<<2);
      const u32 cp  = n | ((((w<<2)|(u32)jt))<<6);
      const u32 base = cp ^ gsw;
      uint4 bv;
      bv.x = lds[base];
      bv.y = lds[base ^ (1u<<12)];
      bv.z = lds[base ^ (2u<<12)];
      bv.w = lds[base ^ (3u<<12)];
      h8 bf; __builtin_memcpy(&bf, &bv, 16);
      f4 rf1 = __builtin_amdgcn_mfma_f32_16x16x32_f16(aRe, bf, z, 0, 0, 0);
      f4 rf2 = __builtin_amdgcn_mfma_f32_16x16x32_f16(aIm, bf, z, 0, 0, 0);
      const u32 c0 = (u32)((__popc(ci&T.erlo[0]) ^ __popc(sw&T.erhi[0])) & 1) ^ gq0;
      const u32 c1 = (u32)((__popc(ci&T.erlo[1]) ^ __popc(sw&T.erhi[1])) & 1) ^ gq1;
      #pragma unroll
      for (int rr = 0; rr < 4; ++rr) {
        const u32 s0 = (c0 ^ (u32)(__popc(T.erhi[0] & (u32)rr) & 1)) & 1u;
        const u32 s1 = (c1 ^ (u32)(__popc(T.erhi[1] & (u32)rr) & 1)) & 1u;
        const float p = rf1[rr]*rf1[rr] + rf2[rr]*rf2[rr];
        z0 += s0 ? -p : p;
        z1 += s1 ? -p : p;
      }
    }
  }

  #pragma unroll
  for (int off = 32; off > 0; off >>= 1) {
    z0 += __shfl_down(z0, off, 64);
    z1 += __shfl_down(z1, off, 64);
  }
  __syncthreads();                       // state reads finished; reuse LDS
  float* red = reinterpret_cast<float*>(lds);
  if ((t & 63u) == 0u) { red[(t>>6)*2] = z0; red[(t>>6)*2+1] = z1; }
  __syncthreads();
  if (t == 0) {
    float a0s = 0.f, a1s = 0.f;
    #pragma unroll
    for (int kk = 0; kk < 16; ++kk) { a0s += red[2*kk]; a1s += red[2*kk+1]; }
    out[2*s]   = a0s;
    out[2*s+1] = a1s;
  }
}

extern "C" void kernel_launch(void* const* d_in, const int* in_sizes, int n_in,
                              void* d_out, int out_size, void* d_ws, size_t ws_size,
                              hipStream_t stream) {
  const float* x = (const float*)d_in[0];   // (4096, 14) f32
  const float* w = (const float*)d_in[1];   // (6, 14, 3) f32
  float* out = (float*)d_out;               // (4096, 2) f32
  u32* gA = (u32*)d_ws;                     // 24*2*64*4 u32 = 48 KiB
  const int B = in_sizes[0] / NQ;

  const AllTables T = qct::make_all();      // deterministic, bounded (R8)

  gate_kernel<<<1, BLOCK, 0, stream>>>(w, gA);

  const size_t lds_bytes = (size_t)NSTATE * sizeof(u32);   // 65536 B
  (void)hipFuncSetAttribute(reinterpret_cast<const void*>(qc_kernel),
                            hipFuncAttributeMaxDynamicSharedMemorySize,
                            (int)lds_bytes);
  qc_kernel<<<B, BLOCK, lds_bytes, stream>>>(x, (const uint4*)gA, out, T);
}

// Round 12
// 646.639 us; speedup vs baseline: 1.0374x; 1.0374x over previous
//
#include <hip/hip_runtime.h>
#include <string.h>

// Quantum classifier fwd: 14 qubits, batch 4096, 6 StronglyEntanglingLayers.
// Round 12 = R11 (R8 conflict-free tables, MFMA, roles-kept reads)
//          + b128 WRITES: W pinned with W(e12)=e0, W(e13)=e1 so the 4 output
//            regs store as one aligned ds_write_b128; per-column role-swap on
//            the write side folded into the tables (V = W ∘ role-fold, linear)
//          + no swt/sw held across barrier -> only po4[4] live (no spills)
// Reads stay 16xb32 (b128 both sides impossible in-place: W injectivity).
// Per-pass fallback to 4xb32 writes if the pin is inconsistent (uniform branch).

#define NQ     14
#define NL     6
#define NSTATE 16384
#define BLOCK  1024
#define NPASS  24

typedef unsigned u32;
typedef _Float16 h8  __attribute__((ext_vector_type(8)));
typedef _Float16 h2v __attribute__((ext_vector_type(2)));
typedef __fp16   p2v __attribute__((ext_vector_type(2)));
typedef float    f4  __attribute__((ext_vector_type(4)));

struct AllTables {
  u32 rhoc[NPASS][4];    // pass roles compressed to col-index space (10-bit)
  u32 wColV[NPASS-1][10];// write map V columns (role-fold included)
  u32 wQ[NPASS-1][2];    // images of old gamma-high addr bits {4,5}
  u32 wGam[NPASS-1][2];  // images of old gamma-low dims {e12,e13} (1,2 if vec)
  u32 a0[10], b0[16];    // init scatter (= W_0 over original basis)
  u32 erlo[2], erhi[2];  // expectation sign rows (col-index / gamma spaces)
  int check;
};

// gamma bit i lives at address bit GB[i]; col bit jc at CB[jc]
static const int GBh[4]  = {12,13,4,5};
static const int CBh[10] = {0,1,2,3,6,7,8,9,10,11};

// ---------------- host-side GF(2) machinery ----------------
namespace qct {

struct GF2 { unsigned short r[NQ]; };
static GF2 gf2_id(){ GF2 m{}; for(int i=0;i<NQ;++i) m.r[i]=(unsigned short)(1u<<i); return m; }
static GF2 gf2_mul(const GF2& A, const GF2& B){
  GF2 C{};
  for(int i=0;i<NQ;++i){ u32 v=0; for(int k=0;k<NQ;++k) if((A.r[i]>>k)&1) v^=B.r[k]; C.r[i]=(unsigned short)v; }
  return C;
}
static GF2 cnotF(int c, int t){
  GF2 F=gf2_id();
  F.r[13-t]=(unsigned short)((1u<<(13-t))|(1u<<(13-c)));
  return F;
}

struct Lin { u32 c[14]; };
static u32 lapply(const Lin& L, u32 x){ u32 r=0; for(int j=0;j<14;++j) if((x>>j)&1u) r^=L.c[j]; return r; }
static Lin lcompose(const Lin& A, const Lin& B){ Lin R{}; for(int j=0;j<14;++j) R.c[j]=lapply(A,B.c[j]); return R; }
static Lin lident(){ Lin L{}; for(int j=0;j<14;++j) L.c[j]=1u<<j; return L; }
static Lin linverse(const Lin& L){
  u32 rows[14]={0}, inv[14]={0};
  for(int i=0;i<14;++i){ u32 r=0; for(int j=0;j<14;++j) r|=((L.c[j]>>i)&1u)<<j; rows[i]=r; inv[i]=1u<<i; }
  for(int col=0; col<14; ++col){
    int piv=-1;
    for(int i=col;i<14;++i) if((rows[i]>>col)&1u){piv=i;break;}
    if(piv<0) continue;
    u32 tr=rows[col]; rows[col]=rows[piv]; rows[piv]=tr;
    tr=inv[col]; inv[col]=inv[piv]; inv[piv]=tr;
    for(int i=0;i<14;++i) if(i!=col && ((rows[i]>>col)&1u)){ rows[i]^=rows[col]; inv[i]^=inv[col]; }
  }
  Lin R{};
  for(int j=0;j<14;++j){ u32 cc=0; for(int i=0;i<14;++i) cc|=((inv[i]>>j)&1u)<<i; R.c[j]=cc; }
  return R;
}
static u32 roletrans(const Lin& invS, u32 rho){
  u32 r=0;
  for(int j=0;j<14;++j) r |= (u32)(__builtin_popcount(invS.c[j]&rho)&1) << j;
  return r;
}

struct Span14 { u32 E[14]; u32 EI[14]; };
static void span_init(Span14& S){ for(int i=0;i<14;++i){S.E[i]=0;S.EI[i]=0;} }
static int top14(u32 v){ for(int i=13;i>=0;--i) if((v>>i)&1u) return i; return -1; }
struct Red { u32 v; u32 img; };
static Red span_reduce(const Span14& S, u32 v){
  u32 img=0;
  while(v){
    int b=top14(v);
    if(!S.E[b]) break;
    v^=S.E[b]; img^=S.EI[b];
  }
  Red r; r.v=v; r.img=img; return r;
}
static bool span_add(Span14& S, u32 v, u32 img){
  Red r=span_reduce(S,v);
  if(!r.v) return false;
  int b=top14(r.v);
  S.E[b]=r.v; S.EI[b]=img^r.img;
  return true;
}
static bool span_has(const Span14& S, u32 v){ Red r=span_reduce(S,v); return r.v==0; }

static u32 cmprs_col(u32 v){ u32 r=0; for(int j=0;j<10;++j) r |= ((v>>CBh[j])&1u)<<j; return r; }
static u32 cmprs_gam(u32 v){ u32 r=0; for(int i=0;i<4;++i)  r |= ((v>>GBh[i])&1u)<<i; return r; }

static AllTables make_all(){
  AllTables T; memset(&T,0,sizeof(T)); T.check=1;
  u32 MU[84]={0}, RHO[84]={0}; u32 er0=0, er1=0;
  {
    GF2 G=gf2_id(), H=gf2_id();
    for(int l=0;l<NL;++l){
      for(int q=0;q<NQ;++q){
        int idx=l*NQ+q, bit=13-q;
        u32 m=0;
        for(int r=0;r<NQ;++r) m |= ((u32)((H.r[r]>>bit)&1u))<<r;
        MU[idx]=m; RHO[idx]=G.r[bit];
        if(!(__builtin_popcount(m & (u32)G.r[bit])&1)) T.check=0;
      }
      int rr=(l%(NQ-1))+1;
      GF2 C=gf2_id(), Ci=gf2_id();
      for(int q=0;q<NQ;++q){
        GF2 F=cnotF(q,(q+rr)%NQ);
        C=gf2_mul(C,F); Ci=gf2_mul(F,Ci);
      }
      G=gf2_mul(Ci,G); H=gf2_mul(H,C);
    }
    er0=G.r[13]; er1=G.r[12];
  }
  Lin S=lident();
  u32 lo_prev[4]={0,0,0,0};
  for(int b=0;b<NPASS;++b){
    const int layer=b>>2, g=b&3;
    const int ng=(g<3)?4:2, q0=(g<3)?4*g:12;
    u32 cin[4]={0,0,0,0};
    for(int i=0;i<ng;++i) cin[i]=lapply(S,MU[layer*NQ+q0+i]);
    if(ng==2){
      // free directions: orthogonal to both real roles, independent of
      // {e12,e13 (pin), cin[0..1]}
      Lin invS=linverse(S);
      u32 rp0=roletrans(invS,RHO[layer*NQ+12]);
      u32 rp1=roletrans(invS,RHO[layer*NQ+13]);
      int got=0;
      for(u32 cs=1; cs<16384u && got<2; ++cs){
        u32 v=(cs*2654435761u)&16383u;
        if(!v) continue;
        if(__builtin_popcount(v&rp0)&1) continue;
        if(__builtin_popcount(v&rp1)&1) continue;
        Span14 tmp; span_init(tmp); bool ind=true;
        if(b>=1){ span_add(tmp,1u<<12,0); span_add(tmp,1u<<13,0); }
        for(int i=0;i<2+got;++i) if(!span_add(tmp,cin[i],0)) ind=false;
        if(ind && span_add(tmp,v,0)){ cin[2+got]=v; ++got; }
      }
      if(got<2) T.check=0;
    }
    // ---- W build: attempt 0 = pinned (b128 writes), attempt 1 = fallback ----
    Lin W=lident();
    u32 fold_used[10]={0,0,0,0,0,0,0,0,0,0};
    bool built=false;
    for(int attempt=0; attempt<2 && !built; ++attempt){
      const bool usePin = (b>=1) && (attempt==0);
      Span14 SI; span_init(SI);
      Span14 IM; span_init(IM);
      bool ok=true;
      if(usePin){
        if(!span_add(SI,1u<<12,1u)) ok=false;
        if(!span_add(IM,1u,0))      ok=false;
        if(!span_add(SI,1u<<13,2u)) ok=false;
        if(!span_add(IM,2u,0))      ok=false;
      }
      for(int i=0;i<4 && ok;++i){
        if(!span_add(SI,cin[i],1u<<GBh[i])) ok=false;
        if(!span_add(IM,1u<<GBh[i],0))      ok=false;
      }
      // gamma-domain completion: dims {12,13,4,5}
      const int gd[4]={12,13,4,5};
      u32 wg[4]={0,0,0,0};
      for(int i=0;i<4 && ok;++i){
        u32 d=1u<<gd[i];
        Red rr=span_reduce(SI,d);
        if(rr.v==0){ wg[i]=rr.img; }
        else {
          u32 img=0; bool f=false;
          for(u32 fm=1; fm<4096u && !f; ++fm){
            u32 cand=(fm<<2)&16383u;            // bits 0,1 = 0
            if(cand && !span_has(IM,cand)){img=cand;f=true;}
          }
          if(!f){ok=false;break;}
          span_add(SI,d,img); span_add(IM,img,0); wg[i]=img;
        }
        if(usePin && i>=2 && (wg[i]&3u)) ok=false;   // wQ alignment
      }
      // role-fold for col dims (uses roles of pass b-1 = lo_prev)
      u32 fold[10];
      for(int jc=0;jc<10;++jc){
        u32 xx=0;
        for(int i=0;i<4;++i) if((lo_prev[i]>>jc)&1u) xx^=wg[i];
        fold[jc]=xx;
      }
      // col-dim completion: jc 0..3 = n, 4,5 = jt, 6..9 = w
      static const u32 patt[4]={4u,8u,16u,0u};
      for(int jc=0;jc<10 && ok;++jc){
        u32 d=1u<<CBh[jc];
        Red rr=span_reduce(SI,d);
        if(rr.v==0){
          if(usePin && (((rr.img^fold[jc])&3u)!=0u)) ok=false;  // V align
          continue;
        }
        u32 img=0; bool f=false;
        if(usePin){
          u32 base=(fold[jc]&3u) ^ ((jc<4)?patt[jc]:0u);
          for(u32 fm=0; fm<512u && !f; ++fm){
            u32 cand=(base ^ (fm<<5))&16383u;
            if(cand && !span_has(IM,cand)){img=cand;f=true;}
          }
          for(u32 fm=0; fm<4096u && !f; ++fm){  // relax bank, keep align
            u32 cand=((fold[jc]&3u) ^ (fm<<2))&16383u;
            if(cand && !span_has(IM,cand)){img=cand;f=true;}
          }
        } else {
          u32 pref=((jc<4)?((1u<<jc)^fold[jc]):0u)&16383u;   // R8 shaping
          for(u32 fm=0; fm<512u && !f; ++fm){
            u32 cand=(pref^(fm<<5))&16383u;
            if(cand && !span_has(IM,cand)){img=cand;f=true;}
          }
          for(u32 fm=1; fm<16384u && !f; ++fm){
            u32 cand=fm;
            if(!span_has(IM,cand)){img=cand;f=true;}
          }
        }
        if(!f){ok=false;break;}
        span_add(SI,d,img); span_add(IM,img,0);
      }
      if(ok){
        for(int jb=0;jb<14 && ok;++jb){
          Red rr=span_reduce(SI,1u<<jb);
          if(rr.v) ok=false; else W.c[jb]=rr.img;
        }
      }
      if(ok){
        for(int i=0;i<4;++i) if(lapply(W,cin[i])!=(1u<<GBh[i])) ok=false;
      }
      if(ok){
        for(int jc=0;jc<10;++jc) fold_used[jc]=fold[jc];
        built=true;
      }
    }
    if(!built) T.check=0;
    if(b==0){
      for(int j=0;j<10;++j) T.a0[j]=W.c[j];
      for(int gm=0;gm<16;++gm){ u32 xx=0; for(int i=0;i<4;++i) if((gm>>i)&1) xx^=W.c[10+i]; T.b0[gm]=xx; }
    } else {
      for(int jc=0;jc<10;++jc) T.wColV[b-1][jc]=W.c[CBh[jc]]^fold_used[jc];
      T.wQ[b-1][0]=W.c[4];  T.wQ[b-1][1]=W.c[5];
      T.wGam[b-1][0]=W.c[12]; T.wGam[b-1][1]=W.c[13];
    }
    S=lcompose(W,S);
    Lin invS2=linverse(S);
    for(int i=0;i<4;++i) T.rhoc[b][i]=0;
    for(int i=0;i<ng;++i){
      u32 rp=roletrans(invS2,RHO[layer*NQ+q0+i]);
      for(int ii=0;ii<4;++ii){
        u32 bit=(rp>>GBh[ii])&1u;
        if(bit != (u32)((ii==i)?1:0)) T.check=0;            // canonical role
      }
      if(lapply(S,MU[layer*NQ+q0+i]) != (1u<<GBh[i])) T.check=0; // canonical mask
      T.rhoc[b][i]=cmprs_col(rp);
    }
    for(int i=0;i<4;++i) lo_prev[i]=T.rhoc[b][i];
  }
  Lin invF=linverse(S);
  u32 e0=roletrans(invF,er0), e1=roletrans(invF,er1);
  T.erlo[0]=cmprs_col(e0); T.erhi[0]=cmprs_gam(e0);
  T.erlo[1]=cmprs_col(e1); T.erhi[1]=cmprs_gam(e1);
  return T;
}

} // namespace qct

// ---------------- device code ----------------

// pre-kernel: per-lane MFMA A-fragments (identical to R8/R11 — verified).
__global__ void gate_kernel(const float* __restrict__ wgt, u32* __restrict__ gA){
  __shared__ float us[84][8];
  const int t = threadIdx.x;
  if (t < 84) {
    const float phi=wgt[3*t+0], th=wgt[3*t+1], om=wgt[3*t+2];
    const float ct=cosf(0.5f*th), stt=sinf(0.5f*th);
    const float aa=0.5f*(phi+om), bb=0.5f*(phi-om);
    const float ca=cosf(aa), sa=sinf(aa);
    const float cb=cosf(bb), sb=sinf(bb);
    us[t][0]= ca*ct;  us[t][1]=-sa*ct;
    us[t][2]=-cb*stt; us[t][3]=-sb*stt;
    us[t][4]= cb*stt; us[t][5]=-sb*stt;
    us[t][6]= ca*ct;  us[t][7]= sa*ct;
  }
  __syncthreads();
  for (int task = t; task < NPASS*64; task += (int)blockDim.x) {
    const int p = task >> 6, l = task & 63;
    const int m = l & 15, gb = ((l>>4)&3)*4;
    const int layer = p>>2, g = p&3;
    const int ng = (g<3)?4:2, q0 = (g<3)?4*g:12;
    u32 rre[4], rim[4];
    for (int r = 0; r < 4; ++r) {
      const int gam = gb + r;
      float ure=1.f, uim=0.f; bool zero=false;
      for (int sl = 0; sl < 4; ++sl) {
        const int mb=(m>>sl)&1, cbit=(gam>>sl)&1;
        float fre, fim;
        if (sl < ng) {
          const float* u = us[layer*NQ + q0 + sl];
          fre = u[(mb*2+cbit)*2]; fim = u[(mb*2+cbit)*2+1];
        } else {
          if (mb != cbit) zero = true;
          fre = 1.f; fim = 0.f;
        }
        const float nre = ure*fre - uim*fim;
        const float nim = ure*fim + uim*fre;
        ure = nre; uim = nim;
      }
      if (zero) { ure = 0.f; uim = 0.f; }
      h2v a; a.x=(_Float16)ure;  a.y=(_Float16)(-uim);
      h2v bq; bq.x=(_Float16)uim; bq.y=(_Float16)ure;
      __builtin_memcpy(&rre[r], &a, 4);
      __builtin_memcpy(&rim[r], &bq, 4);
    }
    u32* o0 = gA + ((size_t)(p*2+0)*64 + l)*4;
    u32* o1 = gA + ((size_t)(p*2+1)*64 + l)*4;
    o0[0]=rre[0]; o0[1]=rre[1]; o0[2]=rre[2]; o0[3]=rre[3];
    o1[0]=rim[0]; o1[1]=rim[1]; o1[2]=rim[2]; o1[3]=rim[3];
  }
}

extern "C" __global__ void __launch_bounds__(BLOCK, 8)
qc_kernel(const float* __restrict__ x, const uint4* __restrict__ gA,
          float* __restrict__ out, const AllTables T){
  extern __shared__ u32 lds[];                // 16384 u32 = 64 KiB (state)
  const u32 t = threadIdx.x;
  const u32 s = blockIdx.x;
  const u32 l = t & 63u, w = t >> 6;
  const u32 q = (l >> 4) & 3u, n = l & 15u;

  // --- encoding angles (LDS scratch overlaps state; barrier-ordered) ---
  float* encf = reinterpret_cast<float*>(lds);
  if (t < NQ) {
    const float h = x[s*NQ + t] * 1.57079632679489662f;
    encf[2*t]   = cosf(h);
    encf[2*t+1] = sinf(h);
  }
  __syncthreads();

  // --- init: product state scattered through W_0 ---
  {
    float pr = 1.0f;
    #pragma unroll
    for (int b = 0; b < 10; ++b) pr *= encf[2*(13-b) + ((t>>b)&1u)];
    float e[8];
    #pragma unroll
    for (int j = 0; j < 8; ++j) e[j] = encf[j];
    __syncthreads();
    u32 a0f = 0;
    #pragma unroll
    for (int j = 0; j < 10; ++j) a0f ^= (0u-((t>>j)&1u)) & T.a0[j];
    #pragma unroll
    for (int i = 0; i < 16; ++i) {
      float vv = pr;
      #pragma unroll
      for (int bq = 0; bq < 4; ++bq) vv *= e[2*(3-bq) + ((i>>bq)&1)];
      h2v hv; hv.x = (_Float16)vv; hv.y = (_Float16)0.0f;
      u32 av; __builtin_memcpy(&av, &hv, 4);
      lds[a0f ^ T.b0[i]] = av;
    }
  }
  __syncthreads();

  const f4 z = {0.f, 0.f, 0.f, 0.f};

  // --- passes 0..22: R8 reads + MFMA + pack pre-barrier + vectorized scatter ---
  #pragma unroll 1
  for (int k = 0; k < NPASS-1; ++k) {
    const uint4 ar4 = gA[(size_t)(k*2+0)*64 + l];
    const uint4 ai4 = gA[(size_t)(k*2+1)*64 + l];
    h8 aRe, aIm;
    __builtin_memcpy(&aRe, &ar4, 16);
    __builtin_memcpy(&aIm, &ai4, 16);
    const u32 r0 = T.rhoc[k][0], r1 = T.rhoc[k][1];
    const u32 r2 = T.rhoc[k][2], r3 = T.rhoc[k][3];

    uint4 po4[4];
    #pragma unroll
    for (int jt = 0; jt < 4; ++jt) {
      const u32 ci = (w<<6) | ((u32)jt<<4) | n;               // col index
      const u32 sw = (u32)(__popc(ci&r0)&1) | ((u32)(__popc(ci&r1)&1)<<1)
                   | ((u32)(__popc(ci&r2)&1)<<2) | ((u32)(__popc(ci&r3)&1)<<3);
      const u32 gx  = (q<<2) ^ sw;
      const u32 gsw = ((gx&3u)<<12) | ((gx&12u)<<2);          // gamma scatter
      const u32 cp  = n | ((((w<<2)|(u32)jt))<<6);            // col scatter
      const u32 base = cp ^ gsw;
      uint4 bv;
      bv.x = lds[base];
      bv.y = lds[base ^ (1u<<12)];
      bv.z = lds[base ^ (2u<<12)];
      bv.w = lds[base ^ (3u<<12)];
      h8 bf; __builtin_memcpy(&bf, &bv, 16);
      f4 rf1 = __builtin_amdgcn_mfma_f32_16x16x32_f16(aRe, bf, z, 0, 0, 0);
      f4 rf2 = __builtin_amdgcn_mfma_f32_16x16x32_f16(aIm, bf, z, 0, 0, 0);
      uint4 pv;
      { p2v hv = __builtin_amdgcn_cvt_pkrtz(rf1[0], rf2[0]); __builtin_memcpy(&pv.x, &hv, 4); }
      { p2v hv = __builtin_amdgcn_cvt_pkrtz(rf1[1], rf2[1]); __builtin_memcpy(&pv.y, &hv, 4); }
      { p2v hv = __builtin_amdgcn_cvt_pkrtz(rf1[2], rf2[2]); __builtin_memcpy(&pv.z, &hv, 4); }
      { p2v hv = __builtin_amdgcn_cvt_pkrtz(rf1[3], rf2[3]); __builtin_memcpy(&pv.w, &hv, 4); }
      po4[jt] = pv;
    }

    __syncthreads();   // all reads done before any scatter lands

    u32 bw = 0;
    #pragma unroll
    for (int j = 0; j < 4; ++j) bw ^= (0u-((n>>j)&1u)) & T.wColV[k][j];
    #pragma unroll
    for (int j = 0; j < 4; ++j) bw ^= (0u-((w>>j)&1u)) & T.wColV[k][6+j];
    bw ^= (0u-(q&1u))      & T.wQ[k][0];
    bw ^= (0u-((q>>1)&1u)) & T.wQ[k][1];
    const u32 g1 = T.wGam[k][0], g2 = T.wGam[k][1];
    if (g1 == 1u && g2 == 2u) {                 // vectorized path (expected)
      #pragma unroll
      for (int jt = 0; jt < 4; ++jt) {
        const u32 ab = bw ^ ((jt&1)?T.wColV[k][4]:0u) ^ ((jt&2)?T.wColV[k][5]:0u);
        *reinterpret_cast<uint4*>(&lds[ab]) = po4[jt];
      }
    } else {                                    // fallback: 4x b32
      #pragma unroll
      for (int jt = 0; jt < 4; ++jt) {
        const u32 ab = bw ^ ((jt&1)?T.wColV[k][4]:0u) ^ ((jt&2)?T.wColV[k][5]:0u);
        lds[ab]        = po4[jt].x;
        lds[ab^g1]     = po4[jt].y;
        lds[ab^g2]     = po4[jt].z;
        lds[ab^g1^g2]  = po4[jt].w;
      }
    }
    __syncthreads();  // scatter complete before next pass reads
  }

  // --- pass 23 (2-gate) fused with expectation, no store ---
  float z0 = 0.f, z1 = 0.f;
  {
    const int k = NPASS-1;
    const uint4 ar4 = gA[(size_t)(k*2+0)*64 + l];
    const uint4 ai4 = gA[(size_t)(k*2+1)*64 + l];
    h8 aRe, aIm;
    __builtin_memcpy(&aRe, &ar4, 16);
    __builtin_memcpy(&aIm, &ai4, 16);
    const u32 r0 = T.rhoc[k][0], r1 = T.rhoc[k][1];
    const u32 r2 = T.rhoc[k][2], r3 = T.rhoc[k][3];
    const u32 gq0 = (u32)(__popc((q<<2) & T.erhi[0]) & 1);
    const u32 gq1 = (u32)(__popc((q<<2) & T.erhi[1]) & 1);
    #pragma unroll
    for (int jt = 0; jt < 4; ++jt) {
      const u32 ci = (w<<6) | ((u32)jt<<4) | n;
      const u32 sw = (u32)(__popc(ci&r0)&1) | ((u32)(__popc(ci&r1)&1)<<1)
                   | ((u32)(__popc(ci&r2)&1)<<2) | ((u32)(__popc(ci&r3)&1)<<3);
      const u32 gx  = (q<<2) ^ sw;
      const u32 gsw = ((gx&3u)<<12) | ((gx&12u)<<2);
      const u32 cp  = n | ((((w<<2)|(u32)jt))<<6);
      const u32 base = cp ^ gsw;
      uint4 bv;
      bv.x = lds[base];
      bv.y = lds[base ^ (1u<<12)];
      bv.z = lds[base ^ (2u<<12)];
      bv.w = lds[base ^ (3u<<12)];
      h8 bf; __builtin_memcpy(&bf, &bv, 16);
      f4 rf1 = __builtin_amdgcn_mfma_f32_16x16x32_f16(aRe, bf, z, 0, 0, 0);
      f4 rf2 = __builtin_amdgcn_mfma_f32_16x16x32_f16(aIm, bf, z, 0, 0, 0);
      const u32 c0 = (u32)((__popc(ci&T.erlo[0]) ^ __popc(sw&T.erhi[0])) & 1) ^ gq0;
      const u32 c1 = (u32)((__popc(ci&T.erlo[1]) ^ __popc(sw&T.erhi[1])) & 1) ^ gq1;
      #pragma unroll
      for (int rr = 0; rr < 4; ++rr) {
        const u32 s0 = (c0 ^ (u32)(__popc(T.erhi[0] & (u32)rr) & 1)) & 1u;
        const u32 s1 = (c1 ^ (u32)(__popc(T.erhi[1] & (u32)rr) & 1)) & 1u;
        const float p = rf1[rr]*rf1[rr] + rf2[rr]*rf2[rr];
        z0 += s0 ? -p : p;
        z1 += s1 ? -p : p;
      }
    }
  }

  #pragma unroll
  for (int off = 32; off > 0; off >>= 1) {
    z0 += __shfl_down(z0, off, 64);
    z1 += __shfl_down(z1, off, 64);
  }
  __syncthreads();                       // state reads finished; reuse LDS
  float* red = reinterpret_cast<float*>(lds);
  if ((t & 63u) == 0u) { red[(t>>6)*2] = z0; red[(t>>6)*2+1] = z1; }
  __syncthreads();
  if (t == 0) {
    float a0s = 0.f, a1s = 0.f;
    #pragma unroll
    for (int kk = 0; kk < 16; ++kk) { a0s += red[2*kk]; a1s += red[2*kk+1]; }
    out[2*s]   = a0s;
    out[2*s+1] = a1s;
  }
}

extern "C" void kernel_launch(void* const* d_in, const int* in_sizes, int n_in,
                              void* d_out, int out_size, void* d_ws, size_t ws_size,
                              hipStream_t stream) {
  const float* x = (const float*)d_in[0];   // (4096, 14) f32
  const float* w = (const float*)d_in[1];   // (6, 14, 3) f32
  float* out = (float*)d_out;               // (4096, 2) f32
  u32* gA = (u32*)d_ws;                     // 24*2*64*4 u32 = 48 KiB
  const int B = in_sizes[0] / NQ;

  const AllTables T = qct::make_all();      // deterministic, bounded

  gate_kernel<<<1, BLOCK, 0, stream>>>(w, gA);

  const size_t lds_bytes = (size_t)NSTATE * sizeof(u32);   // 65536 B
  (void)hipFuncSetAttribute(reinterpret_cast<const void*>(qc_kernel),
                            hipFuncAttributeMaxDynamicSharedMemorySize,
                            (int)lds_bytes);
  qc_kernel<<<B, BLOCK, lds_bytes, stream>>>(x, (const uint4*)gA, out, T);
}

// Round 13
// 490.863 us; speedup vs baseline: 1.3666x; 1.3174x over previous
//
#include <hip/hip_runtime.h>
#include <string.h>

// Quantum classifier fwd: 14 qubits, batch 4096, 6 StronglyEntanglingLayers.
// Round 13 = R8's PROVEN tables (2.1e6 conflicts) + R12's register discipline.
//  - write-side role-swap folded into wCol (linear fold; addresses identical
//    to R11) -> nothing but po4[4] (16 regs) live across the barrier
//  - per-tile sw via sw0 ^ jtTab (4 popc/pass instead of 16; jt contribution
//    from role bits 4..5, wave-uniform scalar ops)
//  - writes stay 4xb32 with R8 bank shaping (b128 writes move the same bytes
//    through the 128B/clk LDS pipe - no win - and broke shaping in R12)

#define NQ     14
#define NL     6
#define NSTATE 16384
#define BLOCK  1024
#define NPASS  24

typedef unsigned u32;
typedef _Float16 h8  __attribute__((ext_vector_type(8)));
typedef _Float16 h2v __attribute__((ext_vector_type(2)));
typedef __fp16   p2v __attribute__((ext_vector_type(2)));
typedef float    f4  __attribute__((ext_vector_type(4)));

struct AllTables {
  u32 rhoc[NPASS][4];   // pass roles compressed to col-index space (10-bit)
  u32 wCol[NPASS-1][10];// write map cols, ROLE-FOLD INCLUDED (post-processed)
  u32 wGam[NPASS-1][4]; // write map: images of gamma bits
  u32 a0[10], b0[16];   // init scatter (= W_0 over original basis)
  u32 erlo[2], erhi[2]; // expectation sign rows (col-index / gamma spaces)
  int check;
};

// gamma bit i lives at address bit GB[i]; col-index bit j at CB[j]
static const int GBh[4]  = {12,13,4,5};
static const int CBh[10] = {0,1,2,3,6,7,8,9,10,11};

// ---------------- host-side GF(2) machinery (R8, verified) ----------------
namespace qct {

struct GF2 { unsigned short r[NQ]; };
static GF2 gf2_id(){ GF2 m{}; for(int i=0;i<NQ;++i) m.r[i]=(unsigned short)(1u<<i); return m; }
static GF2 gf2_mul(const GF2& A, const GF2& B){
  GF2 C{};
  for(int i=0;i<NQ;++i){ u32 v=0; for(int k=0;k<NQ;++k) if((A.r[i]>>k)&1) v^=B.r[k]; C.r[i]=(unsigned short)v; }
  return C;
}
static GF2 cnotF(int c, int t){
  GF2 F=gf2_id();
  F.r[13-t]=(unsigned short)((1u<<(13-t))|(1u<<(13-c)));
  return F;
}

struct Lin { u32 c[14]; };
static u32 lapply(const Lin& L, u32 x){ u32 r=0; for(int j=0;j<14;++j) if((x>>j)&1u) r^=L.c[j]; return r; }
static Lin lcompose(const Lin& A, const Lin& B){ Lin R{}; for(int j=0;j<14;++j) R.c[j]=lapply(A,B.c[j]); return R; }
static Lin lident(){ Lin L{}; for(int j=0;j<14;++j) L.c[j]=1u<<j; return L; }
static Lin linverse(const Lin& L){
  u32 rows[14]={0}, inv[14]={0};
  for(int i=0;i<14;++i){ u32 r=0; for(int j=0;j<14;++j) r|=((L.c[j]>>i)&1u)<<j; rows[i]=r; inv[i]=1u<<i; }
  for(int col=0; col<14; ++col){
    int piv=-1;
    for(int i=col;i<14;++i) if((rows[i]>>col)&1u){piv=i;break;}
    if(piv<0) continue;
    u32 tr=rows[col]; rows[col]=rows[piv]; rows[piv]=tr;
    tr=inv[col]; inv[col]=inv[piv]; inv[piv]=tr;
    for(int i=0;i<14;++i) if(i!=col && ((rows[i]>>col)&1u)){ rows[i]^=rows[col]; inv[i]^=inv[col]; }
  }
  Lin R{};
  for(int j=0;j<14;++j){ u32 cc=0; for(int i=0;i<14;++i) cc|=((inv[i]>>j)&1u)<<i; R.c[j]=cc; }
  return R;
}
static u32 roletrans(const Lin& invS, u32 rho){
  u32 r=0;
  for(int j=0;j<14;++j) r |= (u32)(__builtin_popcount(invS.c[j]&rho)&1) << j;
  return r;
}

struct Span14 { u32 E[14]; u32 EI[14]; };
static void span_init(Span14& S){ for(int i=0;i<14;++i){S.E[i]=0;S.EI[i]=0;} }
static int top14(u32 v){ for(int i=13;i>=0;--i) if((v>>i)&1u) return i; return -1; }
struct Red { u32 v; u32 img; };
static Red span_reduce(const Span14& S, u32 v){
  u32 img=0;
  while(v){
    int b=top14(v);
    if(!S.E[b]) break;
    v^=S.E[b]; img^=S.EI[b];
  }
  Red r; r.v=v; r.img=img; return r;
}
static bool span_add(Span14& S, u32 v, u32 img){
  Red r=span_reduce(S,v);
  if(!r.v) return false;
  int b=top14(r.v);
  S.E[b]=r.v; S.EI[b]=img^r.img;
  return true;
}
static bool span_has(const Span14& S, u32 v){ Red r=span_reduce(S,v); return r.v==0; }

static u32 cmprs_col(u32 v){ u32 r=0; for(int j=0;j<10;++j) r |= ((v>>CBh[j])&1u)<<j; return r; }
static u32 cmprs_gam(u32 v){ u32 r=0; for(int i=0;i<4;++i)  r |= ((v>>GBh[i])&1u)<<i; return r; }

static AllTables make_all(){
  AllTables T; memset(&T,0,sizeof(T)); T.check=1;
  u32 MU[84]={0}, RHO[84]={0}; u32 er0=0, er1=0;
  {
    GF2 G=gf2_id(), H=gf2_id();
    for(int l=0;l<NL;++l){
      for(int q=0;q<NQ;++q){
        int idx=l*NQ+q, bit=13-q;
        u32 m=0;
        for(int r=0;r<NQ;++r) m |= ((u32)((H.r[r]>>bit)&1u))<<r;
        MU[idx]=m; RHO[idx]=G.r[bit];
        if(!(__builtin_popcount(m & (u32)G.r[bit])&1)) T.check=0;
      }
      int rr=(l%(NQ-1))+1;
      GF2 C=gf2_id(), Ci=gf2_id();
      for(int q=0;q<NQ;++q){
        GF2 F=cnotF(q,(q+rr)%NQ);
        C=gf2_mul(C,F); Ci=gf2_mul(F,Ci);
      }
      G=gf2_mul(Ci,G); H=gf2_mul(H,C);
    }
    er0=G.r[13]; er1=G.r[12];
  }
  Lin S=lident();
  u32 lo_prev[4]={0,0,0,0};
  for(int b=0;b<NPASS;++b){
    const int layer=b>>2, g=b&3;
    const int ng=(g<3)?4:2, q0=(g<3)?4*g:12;
    u32 cin[4]={0,0,0,0};
    for(int i=0;i<ng;++i) cin[i]=lapply(S,MU[layer*NQ+q0+i]);
    if(ng==2){
      Lin invS=linverse(S);
      u32 rp0=roletrans(invS,RHO[layer*NQ+12]);
      u32 rp1=roletrans(invS,RHO[layer*NQ+13]);
      int got=0;
      for(u32 cs=1; cs<16384u && got<2; ++cs){
        u32 v=(cs*2654435761u)&16383u;
        if(!v) continue;
        if(__builtin_popcount(v&rp0)&1) continue;
        if(__builtin_popcount(v&rp1)&1) continue;
        Span14 tmp; span_init(tmp); bool ind=true;
        for(int i=0;i<2+got;++i) if(!span_add(tmp,cin[i],0)) ind=false;
        if(ind){ cin[2+got]=v; ++got; }
      }
      if(got<2) T.check=0;
    }
    // ---- deterministic W build (R8, verbatim) ----
    Span14 SI; span_init(SI);
    Span14 IM; span_init(IM);
    bool ok=true;
    for(int i=0;i<4;++i){
      if(!span_add(SI,cin[i],1u<<GBh[i])) ok=false;
      if(!span_add(IM,1u<<GBh[i],0))      ok=false;
    }
    u32 wg[4]={0,0,0,0};
    for(int i=0;i<4 && ok;++i){
      u32 d=1u<<GBh[i];
      Red rr=span_reduce(SI,d);
      if(rr.v==0){ wg[i]=rr.img; continue; }
      u32 img=0; bool f=false;
      for(u32 fm=0; fm<16384u && !f; ++fm){ u32 cand=d^fm; if(cand && !span_has(IM,cand)){img=cand;f=true;} }
      if(!f){ok=false;break;}
      span_add(SI,d,img); span_add(IM,img,0); wg[i]=img;
    }
    u32 X[4]={0,0,0,0};
    for(int j=0;j<4;++j){ u32 xx=0; for(int i=0;i<4;++i) if((lo_prev[i]>>j)&1u) xx^=wg[i]; X[j]=xx; }
    for(int j=0;j<4 && ok;++j){
      u32 d=1u<<CBh[j];
      if(span_has(SI,d)) continue;
      u32 pref=((1u<<j)^X[j])&16383u;
      u32 img=0; bool f=false;
      for(u32 fm=0; fm<512u && !f; ++fm){ u32 cand=(pref^(fm<<5))&16383u; if(cand && !span_has(IM,cand)){img=cand;f=true;} }
      for(u32 fm=0; fm<16384u && !f; ++fm){ u32 cand=(pref^fm)&16383u; if(cand && !span_has(IM,cand)){img=cand;f=true;} }
      if(!f){ok=false;break;}
      span_add(SI,d,img); span_add(IM,img,0);
    }
    for(int j=4;j<10 && ok;++j){
      u32 d=1u<<CBh[j];
      if(span_has(SI,d)) continue;
      u32 img=0; bool f=false;
      for(u32 fm=0; fm<16384u && !f; ++fm){ u32 cand=d^fm; if(cand && !span_has(IM,cand)){img=cand;f=true;} }
      if(!f){ok=false;break;}
      span_add(SI,d,img); span_add(IM,img,0);
    }
    Lin W=lident();
    if(ok){
      for(int jb=0;jb<14;++jb){
        Red rr=span_reduce(SI,1u<<jb);
        if(rr.v){ok=false;break;}
        W.c[jb]=rr.img;
      }
    }
    if(!ok) T.check=0;
    if(b==0){
      for(int j=0;j<10;++j) T.a0[j]=W.c[j];
      for(int gm=0;gm<16;++gm){ u32 xx=0; for(int i=0;i<4;++i) if((gm>>i)&1) xx^=W.c[10+i]; T.b0[gm]=xx; }
    } else {
      for(int j=0;j<10;++j) T.wCol[b-1][j]=W.c[CBh[j]];
      for(int i=0;i<4;++i)  T.wGam[b-1][i]=W.c[GBh[i]];
    }
    S=lcompose(W,S);
    Lin invS2=linverse(S);
    for(int i=0;i<4;++i) T.rhoc[b][i]=0;
    for(int i=0;i<ng;++i){
      u32 rp=roletrans(invS2,RHO[layer*NQ+q0+i]);
      for(int ii=0;ii<4;++ii){
        u32 bit=(rp>>GBh[ii])&1u;
        if(bit != (u32)((ii==i)?1:0)) T.check=0;            // canonical role
      }
      if(lapply(S,MU[layer*NQ+q0+i]) != (1u<<GBh[i])) T.check=0; // canonical mask
      T.rhoc[b][i]=cmprs_col(rp);
    }
    for(int i=0;i<4;++i) lo_prev[i]=T.rhoc[b][i];
  }
  Lin invF=linverse(S);
  u32 e0=roletrans(invF,er0), e1=roletrans(invF,er1);
  T.erlo[0]=cmprs_col(e0); T.erhi[0]=cmprs_gam(e0);
  T.erlo[1]=cmprs_col(e1); T.erhi[1]=cmprs_gam(e1);

  // ---- fold write-side role-swap into wCol (addresses identical to R11,
  // but the kernel no longer needs swt across the barrier) ----
  for(int k=0;k<NPASS-1;++k)
    for(int jc=0;jc<10;++jc){
      u32 xx=0;
      for(int i=0;i<4;++i) if((T.rhoc[k][i]>>jc)&1u) xx^=T.wGam[k][i];
      T.wCol[k][jc]^=xx;
    }
  return T;
}

} // namespace qct

// ---------------- device code ----------------

// pre-kernel: per-lane MFMA A-fragments (identical to R8/R11 — verified).
__global__ void gate_kernel(const float* __restrict__ wgt, u32* __restrict__ gA){
  __shared__ float us[84][8];
  const int t = threadIdx.x;
  if (t < 84) {
    const float phi=wgt[3*t+0], th=wgt[3*t+1], om=wgt[3*t+2];
    const float ct=cosf(0.5f*th), stt=sinf(0.5f*th);
    const float aa=0.5f*(phi+om), bb=0.5f*(phi-om);
    const float ca=cosf(aa), sa=sinf(aa);
    const float cb=cosf(bb), sb=sinf(bb);
    us[t][0]= ca*ct;  us[t][1]=-sa*ct;
    us[t][2]=-cb*stt; us[t][3]=-sb*stt;
    us[t][4]= cb*stt; us[t][5]=-sb*stt;
    us[t][6]= ca*ct;  us[t][7]= sa*ct;
  }
  __syncthreads();
  for (int task = t; task < NPASS*64; task += (int)blockDim.x) {
    const int p = task >> 6, l = task & 63;
    const int m = l & 15, gb = ((l>>4)&3)*4;
    const int layer = p>>2, g = p&3;
    const int ng = (g<3)?4:2, q0 = (g<3)?4*g:12;
    u32 rre[4], rim[4];
    for (int r = 0; r < 4; ++r) {
      const int gam = gb + r;
      float ure=1.f, uim=0.f; bool zero=false;
      for (int sl = 0; sl < 4; ++sl) {
        const int mb=(m>>sl)&1, cbit=(gam>>sl)&1;
        float fre, fim;
        if (sl < ng) {
          const float* u = us[layer*NQ + q0 + sl];
          fre = u[(mb*2+cbit)*2]; fim = u[(mb*2+cbit)*2+1];
        } else {
          if (mb != cbit) zero = true;
          fre = 1.f; fim = 0.f;
        }
        const float nre = ure*fre - uim*fim;
        const float nim = ure*fim + uim*fre;
        ure = nre; uim = nim;
      }
      if (zero) { ure = 0.f; uim = 0.f; }
      h2v a; a.x=(_Float16)ure;  a.y=(_Float16)(-uim);
      h2v bq; bq.x=(_Float16)uim; bq.y=(_Float16)ure;
      __builtin_memcpy(&rre[r], &a, 4);
      __builtin_memcpy(&rim[r], &bq, 4);
    }
    u32* o0 = gA + ((size_t)(p*2+0)*64 + l)*4;
    u32* o1 = gA + ((size_t)(p*2+1)*64 + l)*4;
    o0[0]=rre[0]; o0[1]=rre[1]; o0[2]=rre[2]; o0[3]=rre[3];
    o1[0]=rim[0]; o1[1]=rim[1]; o1[2]=rim[2]; o1[3]=rim[3];
  }
}

extern "C" __global__ void __launch_bounds__(BLOCK, 8)
qc_kernel(const float* __restrict__ x, const uint4* __restrict__ gA,
          float* __restrict__ out, const AllTables T){
  extern __shared__ u32 lds[];                // 16384 u32 = 64 KiB (state)
  const u32 t = threadIdx.x;
  const u32 s = blockIdx.x;
  const u32 l = t & 63u, w = t >> 6;
  const u32 q = (l >> 4) & 3u, n = l & 15u;

  // --- encoding angles (LDS scratch overlaps state; barrier-ordered) ---
  float* encf = reinterpret_cast<float*>(lds);
  if (t < NQ) {
    const float h = x[s*NQ + t] * 1.57079632679489662f;
    encf[2*t]   = cosf(h);
    encf[2*t+1] = sinf(h);
  }
  __syncthreads();

  // --- init: product state scattered through W_0 ---
  {
    float pr = 1.0f;
    #pragma unroll
    for (int b = 0; b < 10; ++b) pr *= encf[2*(13-b) + ((t>>b)&1u)];
    float e[8];
    #pragma unroll
    for (int j = 0; j < 8; ++j) e[j] = encf[j];
    __syncthreads();
    u32 a0f = 0;
    #pragma unroll
    for (int j = 0; j < 10; ++j) a0f ^= (0u-((t>>j)&1u)) & T.a0[j];
    #pragma unroll
    for (int i = 0; i < 16; ++i) {
      float vv = pr;
      #pragma unroll
      for (int bq = 0; bq < 4; ++bq) vv *= e[2*(3-bq) + ((i>>bq)&1)];
      h2v hv; hv.x = (_Float16)vv; hv.y = (_Float16)0.0f;
      u32 av; __builtin_memcpy(&av, &hv, 4);
      lds[a0f ^ T.b0[i]] = av;
    }
  }
  __syncthreads();

  const f4 z = {0.f, 0.f, 0.f, 0.f};

  // --- passes 0..22: R8 reads + MFMA + pack pre-barrier + folded scatter ---
  #pragma unroll 1
  for (int k = 0; k < NPASS-1; ++k) {
    const uint4 ar4 = gA[(size_t)(k*2+0)*64 + l];
    const uint4 ai4 = gA[(size_t)(k*2+1)*64 + l];
    h8 aRe, aIm;
    __builtin_memcpy(&aRe, &ar4, 16);
    __builtin_memcpy(&aIm, &ai4, 16);
    const u32 r0 = T.rhoc[k][0], r1 = T.rhoc[k][1];
    const u32 r2 = T.rhoc[k][2], r3 = T.rhoc[k][3];

    // sw for jt: sw0 ^ jt-contribution (role bits 4,5; t1/t2 wave-uniform)
    const u32 ci0 = (w<<6) | n;
    const u32 sw0 = (u32)(__popc(ci0&r0)&1) | ((u32)(__popc(ci0&r1)&1)<<1)
                  | ((u32)(__popc(ci0&r2)&1)<<2) | ((u32)(__popc(ci0&r3)&1)<<3);
    const u32 t1 = ((r0>>4)&1u) | (((r1>>4)&1u)<<1) | (((r2>>4)&1u)<<2) | (((r3>>4)&1u)<<3);
    const u32 t2 = ((r0>>5)&1u) | (((r1>>5)&1u)<<1) | (((r2>>5)&1u)<<2) | (((r3>>5)&1u)<<3);

    uint4 po4[4];
    #pragma unroll
    for (int jt = 0; jt < 4; ++jt) {
      const u32 sw = sw0 ^ ((jt&1)?t1:0u) ^ ((jt&2)?t2:0u);
      const u32 gx  = (q<<2) ^ sw;
      const u32 gsw = ((gx&3u)<<12) | ((gx&12u)<<2);          // gamma scatter
      const u32 cp  = n | ((((w<<2)|(u32)jt))<<6);            // col scatter
      const u32 base = cp ^ gsw;
      uint4 bv;
      bv.x = lds[base];
      bv.y = lds[base ^ (1u<<12)];
      bv.z = lds[base ^ (2u<<12)];
      bv.w = lds[base ^ (3u<<12)];
      h8 bf; __builtin_memcpy(&bf, &bv, 16);
      f4 rf1 = __builtin_amdgcn_mfma_f32_16x16x32_f16(aRe, bf, z, 0, 0, 0);
      f4 rf2 = __builtin_amdgcn_mfma_f32_16x16x32_f16(aIm, bf, z, 0, 0, 0);
      uint4 pv;
      { p2v hv = __builtin_amdgcn_cvt_pkrtz(rf1[0], rf2[0]); __builtin_memcpy(&pv.x, &hv, 4); }
      { p2v hv = __builtin_amdgcn_cvt_pkrtz(rf1[1], rf2[1]); __builtin_memcpy(&pv.y, &hv, 4); }
      { p2v hv = __builtin_amdgcn_cvt_pkrtz(rf1[2], rf2[2]); __builtin_memcpy(&pv.z, &hv, 4); }
      { p2v hv = __builtin_amdgcn_cvt_pkrtz(rf1[3], rf2[3]); __builtin_memcpy(&pv.w, &hv, 4); }
      po4[jt] = pv;
    }

    __syncthreads();   // all reads done before any scatter lands

    // write base: role-fold already inside wCol (no sw needed here)
    u32 bw = 0;
    #pragma unroll
    for (int j = 0; j < 4; ++j) bw ^= (0u-((n>>j)&1u)) & T.wCol[k][j];
    #pragma unroll
    for (int j = 0; j < 4; ++j) bw ^= (0u-((w>>j)&1u)) & T.wCol[k][6+j];
    bw ^= (0u-(q&1u))      & T.wGam[k][2];
    bw ^= (0u-((q>>1)&1u)) & T.wGam[k][3];
    const u32 g1 = T.wGam[k][0], g2 = T.wGam[k][1];
    #pragma unroll
    for (int jt = 0; jt < 4; ++jt) {
      const u32 ab = bw ^ ((jt&1)?T.wCol[k][4]:0u) ^ ((jt&2)?T.wCol[k][5]:0u);
      lds[ab]        = po4[jt].x;
      lds[ab^g1]     = po4[jt].y;
      lds[ab^g2]     = po4[jt].z;
      lds[ab^g1^g2]  = po4[jt].w;
    }
    __syncthreads();  // scatter complete before next pass reads
  }

  // --- pass 23 (2-gate) fused with expectation, no store ---
  float z0 = 0.f, z1 = 0.f;
  {
    const int k = NPASS-1;
    const uint4 ar4 = gA[(size_t)(k*2+0)*64 + l];
    const uint4 ai4 = gA[(size_t)(k*2+1)*64 + l];
    h8 aRe, aIm;
    __builtin_memcpy(&aRe, &ar4, 16);
    __builtin_memcpy(&aIm, &ai4, 16);
    const u32 r0 = T.rhoc[k][0], r1 = T.rhoc[k][1];
    const u32 r2 = T.rhoc[k][2], r3 = T.rhoc[k][3];
    const u32 gq0 = (u32)(__popc((q<<2) & T.erhi[0]) & 1);
    const u32 gq1 = (u32)(__popc((q<<2) & T.erhi[1]) & 1);
    #pragma unroll
    for (int jt = 0; jt < 4; ++jt) {
      const u32 ci = (w<<6) | ((u32)jt<<4) | n;
      const u32 sw = (u32)(__popc(ci&r0)&1) | ((u32)(__popc(ci&r1)&1)<<1)
                   | ((u32)(__popc(ci&r2)&1)<<2) | ((u32)(__popc(ci&r3)&1)<<3);
      const u32 gx  = (q<<2) ^ sw;
      const u32 gsw = ((gx&3u)<<12) | ((gx&12u)<<2);
      const u32 cp  = n | ((((w<<2)|(u32)jt))<<6);
      const u32 base = cp ^ gsw;
      uint4 bv;
      bv.x = lds[base];
      bv.y = lds[base ^ (1u<<12)];
      bv.z = lds[base ^ (2u<<12)];
      bv.w = lds[base ^ (3u<<12)];
      h8 bf; __builtin_memcpy(&bf, &bv, 16);
      f4 rf1 = __builtin_amdgcn_mfma_f32_16x16x32_f16(aRe, bf, z, 0, 0, 0);
      f4 rf2 = __builtin_amdgcn_mfma_f32_16x16x32_f16(aIm, bf, z, 0, 0, 0);
      const u32 c0 = (u32)((__popc(ci&T.erlo[0]) ^ __popc(sw&T.erhi[0])) & 1) ^ gq0;
      const u32 c1 = (u32)((__popc(ci&T.erlo[1]) ^ __popc(sw&T.erhi[1])) & 1) ^ gq1;
      #pragma unroll
      for (int rr = 0; rr < 4; ++rr) {
        const u32 s0 = (c0 ^ (u32)(__popc(T.erhi[0] & (u32)rr) & 1)) & 1u;
        const u32 s1 = (c1 ^ (u32)(__popc(T.erhi[1] & (u32)rr) & 1)) & 1u;
        const float p = rf1[rr]*rf1[rr] + rf2[rr]*rf2[rr];
        z0 += s0 ? -p : p;
        z1 += s1 ? -p : p;
      }
    }
  }

  #pragma unroll
  for (int off = 32; off > 0; off >>= 1) {
    z0 += __shfl_down(z0, off, 64);
    z1 += __shfl_down(z1, off, 64);
  }
  __syncthreads();                       // state reads finished; reuse LDS
  float* red = reinterpret_cast<float*>(lds);
  if ((t & 63u) == 0u) { red[(t>>6)*2] = z0; red[(t>>6)*2+1] = z1; }
  __syncthreads();
  if (t == 0) {
    float a0s = 0.f, a1s = 0.f;
    #pragma unroll
    for (int kk = 0; kk < 16; ++kk) { a0s += red[2*kk]; a1s += red[2*kk+1]; }
    out[2*s]   = a0s;
    out[2*s+1] = a1s;
  }
}

extern "C" void kernel_launch(void* const* d_in, const int* in_sizes, int n_in,
                              void* d_out, int out_size, void* d_ws, size_t ws_size,
                              hipStream_t stream) {
  const float* x = (const float*)d_in[0];   // (4096, 14) f32
  const float* w = (const float*)d_in[1];   // (6, 14, 3) f32
  float* out = (float*)d_out;               // (4096, 2) f32
  u32* gA = (u32*)d_ws;                     // 24*2*64*4 u32 = 48 KiB
  const int B = in_sizes[0] / NQ;

  const AllTables T = qct::make_all();      // deterministic, bounded (R8)

  gate_kernel<<<1, BLOCK, 0, stream>>>(w, gA);

  const size_t lds_bytes = (size_t)NSTATE * sizeof(u32);   // 65536 B
  (void)hipFuncSetAttribute(reinterpret_cast<const void*>(qc_kernel),
                            hipFuncAttributeMaxDynamicSharedMemorySize,
                            (int)lds_bytes);
  qc_kernel<<<B, BLOCK, lds_bytes, stream>>>(x, (const uint4*)gA, out, T);
}